// Round 1
// baseline (334.679 us; speedup 1.0000x reference)
//
#include <hip/hip_runtime.h>
#include <cstdint>

#define BATCH 64
#define NPIX 65536
#define TOPK 16384
#define NB 256
#define SEGS 32       // k1 blocks per batch
#define WLO 186       // candidate window low bin (threshold bin ~192)
#define WHI 198       // candidate window high bin
#define NWBIN (WHI - WLO + 1)
#define CAPB 192      // per-block window-candidate slots (expect ~104, sigma~10)
#define NSLOT (SEGS * CAPB)   // 6144
#define FCAP 1024     // threshold-bin rank buffer (expect ~256, sigma~16)
#define WHSTRIDE 16   // padded per-block histogram stride (13 used)

// ---- 256-thread block reduce ----
__device__ __forceinline__ float block_reduce(float acc) {
    __shared__ float w[4];
    __syncthreads();
    #pragma unroll
    for (int off = 32; off > 0; off >>= 1) acc += __shfl_down(acc, off, 64);
    if ((threadIdx.x & 63) == 0) w[threadIdx.x >> 6] = acc;
    __syncthreads();
    return w[0] + w[1] + w[2] + w[3];
}

// p = softmax(a0,a1)[0] = sigmoid(d), d = a0-a1.
// lp = log p = min(d,0)-t ; llp = log(1-p) = -max(d,0)-t, t = log(1+exp(-|d|)).
__device__ __forceinline__ void bce_from_d(float d, float& lp, float& llp) {
    float t = __logf(1.f + __expf(-fabsf(d)));
    lp  = fmaxf(fminf(d, 0.f) - t, -100.f);
    llp = fmaxf(-fmaxf(d, 0.f) - t, -100.f);
}

__device__ __forceinline__ int vkey(float v) {
    return (int)fminf(v * 256.0f, 255.0f);   // monotone bucket map, v in [0,1)
}

// ---------------------------------------------------------------------------
// K0: zero per-batch ticket counters + out (workspace is poisoned, not zero).
// ---------------------------------------------------------------------------
__global__ void k0_init(uint32_t* __restrict__ bdone, float* __restrict__ out) {
    if (threadIdx.x < BATCH) bdone[threadIdx.x] = 0u;
    if (threadIdx.x == 0) out[0] = 0.f;
}

// ---------------------------------------------------------------------------
// Fused K1: proven round-9 main pass, PLUS:
//  - per-block 13-bin window histogram (kills old k4 pass A entirely)
//  - device-fence release + per-batch ticket; the 32nd (last) block of each
//    batch runs the finalize in-kernel with its 256 threads.
// Finalize overlaps with other batches' main-loop blocks; only the last
// batch's finalize is exposed. Old 64-block k4 dispatch is gone.
// ---------------------------------------------------------------------------
__global__ __launch_bounds__(256, 4) void k1_fused(
    const float4* __restrict__ sc, const float4* __restrict__ gn,
    const float2* __restrict__ tokp,
    float* __restrict__ pk1, float* __restrict__ psel, float* __restrict__ phi,
    uint32_t* __restrict__ gcc,
    uint32_t* __restrict__ cvb, uint32_t* __restrict__ cvi,
    uint32_t* __restrict__ cvd,
    uint32_t* __restrict__ whist, uint32_t* __restrict__ bdone,
    const float4* __restrict__ tok4,
    const float2* __restrict__ sc2, const float2* __restrict__ gn2,
    float* __restrict__ out)
{
    __shared__ uint32_t bvb[CAPB], bvi[CAPB], bvd[CAPB];
    __shared__ uint32_t sh_wh[NWBIN];
    __shared__ uint32_t ccount;
    __shared__ uint32_t sh_ticket;
    // finalize-phase shared state
    __shared__ uint32_t fvb[FCAP], fvi[FCAP];
    __shared__ float    fdf[FCAP];
    __shared__ uint32_t fh[NB];
    __shared__ uint32_t wc[NWBIN];
    __shared__ uint32_t fcnt;
    __shared__ int      sh_sb, sh_ovf;
    __shared__ uint32_t sh_rem;

    const int tid = threadIdx.x;
    if (tid < CAPB) { bvb[tid] = 0u; bvi[tid] = 0u; bvd[tid] = 0u; }
    if (tid < NWBIN) sh_wh[tid] = 0u;
    if (tid == 0) ccount = 0u;
    __syncthreads();

    const int b   = blockIdx.x >> 5;
    const int seg = blockIdx.x & (SEGS - 1);
    const int pairbase = b * (NPIX / 2) + seg * 1024;   // 1024 pairs / block
    float acc = 0.f, asel = 0.f, chi = 0.f;

    #pragma unroll
    for (int it = 0; it < 4; ++it) {
        int j = pairbase + it * 256 + tid;
        float4 s = sc[j];
        float4 g = gn[j];
        float2 tk = tokp[j];
        int px0 = (j - b * (NPIX / 2)) * 2;             // batch-local pixel idx
        {
            float d = (s.x + g.x) - (s.y + g.y);
            float lp, llp; bce_from_d(d, lp, llp);
            acc += llp;
            float diff = lp - llp;
            int k = vkey(tk.x);
            if (k > WHI) { asel += diff; chi += 1.f; }
            else if (k >= WLO) {
                uint32_t p = atomicAdd(&ccount, 1u);
                if (p < CAPB) {
                    bvb[p] = __float_as_uint(tk.x);
                    bvi[p] = (uint32_t)px0;
                    bvd[p] = __float_as_uint(diff);
                }
            }
        }
        {
            float d = (s.z + g.z) - (s.w + g.w);
            float lp, llp; bce_from_d(d, lp, llp);
            acc += llp;
            float diff = lp - llp;
            int k = vkey(tk.y);
            if (k > WHI) { asel += diff; chi += 1.f; }
            else if (k >= WLO) {
                uint32_t p = atomicAdd(&ccount, 1u);
                if (p < CAPB) {
                    bvb[p] = __float_as_uint(tk.y);
                    bvi[p] = (uint32_t)(px0 + 1);
                    bvd[p] = __float_as_uint(diff);
                }
            }
        }
    }
    __syncthreads();
    const uint32_t cc = ccount;
    // per-block window histogram from the compacted slots (~104 LDS atomics)
    {
        uint32_t nsl = cc < CAPB ? cc : CAPB;
        if (tid < nsl) {
            int k = vkey(__uint_as_float(bvb[tid]));
            atomicAdd(&sh_wh[k - WLO], 1u);
        }
    }
    // publish full fixed-size slot block (unused slots are zero sentinels)
    const size_t cbase = (size_t)blockIdx.x * CAPB;
    if (tid < CAPB) {
        cvb[cbase + tid] = bvb[tid];
        cvi[cbase + tid] = bvi[tid];
        cvd[cbase + tid] = bvd[tid];
    }
    if (tid == 0) gcc[blockIdx.x] = cc;

    float t1 = block_reduce(acc);    // internal barriers also fence sh_wh atomics
    float t2 = block_reduce(asel);
    float t3 = block_reduce(chi);
    if (tid == 0) {
        pk1[blockIdx.x]  = t1;
        psel[blockIdx.x] = t2;
        phi[blockIdx.x]  = t3;
    }
    if (tid < NWBIN) whist[(size_t)blockIdx.x * WHSTRIDE + tid] = sh_wh[tid];

    // ---- release + per-batch ticket (canonical last-block pattern) ----
    __threadfence();                 // agent-scope release: wbl2 across XCDs
    __syncthreads();                 // all threads' stores+fences precede ticket
    if (tid == 0) sh_ticket = atomicAdd(&bdone[b], 1u);
    __syncthreads();
    if (sh_ticket != SEGS - 1) return;

    // =================== FINALIZE (last block of batch b) ===================
    __threadfence();                 // agent-scope acquire: inv stale caches

    if (tid == 0) { fcnt = 0u; sh_sb = -1; sh_ovf = 0; sh_rem = 1u; }
    __syncthreads();

    if (tid < SEGS && gcc[b * SEGS + tid] > CAPB) sh_ovf = 1;
    // window counts: sum the 32 published per-block histograms (tiny)
    if (tid < NWBIN) {
        uint32_t u = 0;
        #pragma unroll
        for (int s = 0; s < SEGS; ++s)
            u += whist[(size_t)(b * SEGS + s) * WHSTRIDE + tid];
        wc[tid] = u;
    }
    float chl = (tid < SEGS) ? phi[b * SEGS + tid] : 0.f;
    float chf = block_reduce(chl);   // exact: integer-valued floats < 2^24
    if (tid == 0) {
        uint32_t cnt_hi = (uint32_t)(chf + 0.5f);
        if (cnt_hi >= TOPK) sh_ovf = 1;  // split bin above window
        else {
            uint32_t cum = cnt_hi;       // S[WHI+1]
            int found = -1; uint32_t rem = 1u;
            for (int jj = WHI; jj >= WLO; --jj) {
                uint32_t nc = cum + wc[jj - WLO];     // S[jj]
                if (nc >= TOPK) { found = jj; rem = TOPK - cum; break; }
                cum = nc;
            }
            if (found < 0) sh_ovf = 1;   // split bin below window
            else { sh_sb = found; sh_rem = rem; }
        }
    }
    __syncthreads();

    bool fast = (sh_ovf == 0);
    const int sb = sh_sb;
    const size_t fbase = (size_t)b * NSLOT;
    float fac = (tid < SEGS) ? pk1[b * SEGS + tid] : 0.f;   // base llp

    if (fast) {
        if (tid < SEGS) fac += psel[b * SEGS + tid];        // key > WHI diffs
        // single L2/L3-hot walk; vb+vd loaded unconditionally (no dep chain)
        #pragma unroll
        for (int it = 0; it < NSLOT / 256; ++it) {          // 24 iters
            int t = it * 256 + tid;
            uint32_t vb = cvb[fbase + t];
            uint32_t vd = cvd[fbase + t];
            int k = vkey(__uint_as_float(vb));
            if (k > sb) fac += __uint_as_float(vd);
            else if (k == sb) {
                uint32_t p = atomicAdd(&fcnt, 1u);
                if (p < FCAP) {
                    fvb[p] = vb;
                    fvi[p] = cvi[fbase + t] & (NPIX - 1);
                    fdf[p] = __uint_as_float(vd);
                }
            }
        }
        __syncthreads();
        if (fcnt > FCAP) fast = false;   // uniform decision (shared value)
        if (fast) {
            const uint32_t cnt = fcnt, rem = sh_rem;
            for (uint32_t j = tid; j < cnt; j += 256) {
                const uint32_t mb = fvb[j], mi = fvi[j];
                uint32_t rank = 0;
                for (uint32_t i = 0; i < cnt; ++i) {
                    uint32_t ob = fvb[i];
                    rank += (ob > mb) || (ob == mb && fvi[i] < mi);
                }
                if (rank < rem) fac += fdf[j];
            }
        }
    }

    if (!fast) {
        // ---- exact fallback: full per-batch recount + recompute ----
        fac = (tid < SEGS) ? pk1[b * SEGS + tid] : 0.f;     // reset to base
        for (int i = tid; i < NB; i += 256) fh[i] = 0u;
        if (tid == 0) fcnt = 0u;
        __syncthreads();
        const float4* tbase = tok4 + (size_t)b * (NPIX / 4);
        for (int it = 0; it < NPIX / 4 / 256; ++it) {       // 64 iters
            float4 v = tbase[it * 256 + tid];
            atomicAdd(&fh[vkey(v.x)], 1u);
            atomicAdd(&fh[vkey(v.y)], 1u);
            atomicAdd(&fh[vkey(v.z)], 1u);
            atomicAdd(&fh[vkey(v.w)], 1u);
        }
        __syncthreads();
        if (tid == 0) {
            uint32_t cum = 0; int bin = NB - 1;
            for (; bin > 0; --bin) {
                if (cum + fh[bin] >= TOPK) break;
                cum += fh[bin];
            }
            sh_sb = bin; sh_rem = TOPK - cum;
        }
        __syncthreads();
        const int sb2 = sh_sb; const uint32_t rem2 = sh_rem;
        for (int it = 0; it < NPIX / 4 / 256; ++it) {
            int j = it * 256 + tid;
            float4 v = tbase[j];
            int px = j * 4;
            float fv[4] = {v.x, v.y, v.z, v.w};
            #pragma unroll
            for (int q = 0; q < 4; ++q) {
                int k = vkey(fv[q]);
                if (k > sb2) {
                    size_t idx = (size_t)b * NPIX + (px + q);
                    float2 S = sc2[idx]; float2 G = gn2[idx];
                    float d = (S.x + G.x) - (S.y + G.y);
                    float lp, llp; bce_from_d(d, lp, llp);
                    fac += lp - llp;
                } else if (k == sb2) {
                    uint32_t p = atomicAdd(&fcnt, 1u);
                    if (p < FCAP) { fvb[p] = __float_as_uint(fv[q]); fvi[p] = (uint32_t)(px + q); }
                }
            }
        }
        __syncthreads();
        const uint32_t cnt2 = min(fcnt, (uint32_t)FCAP);
        for (uint32_t j = tid; j < cnt2; j += 256) {
            const uint32_t mb = fvb[j], mi = fvi[j];
            uint32_t rank = 0;
            for (uint32_t i = 0; i < cnt2; ++i) {
                uint32_t ob = fvb[i];
                rank += (ob > mb) || (ob == mb && fvi[i] < mi);
            }
            if (rank < rem2) {
                size_t idx = (size_t)b * NPIX + (mi & (NPIX - 1));
                float2 S = sc2[idx]; float2 G = gn2[idx];
                float d = (S.x + G.x) - (S.y + G.y);
                float lp, llp; bce_from_d(d, lp, llp);
                fac += lp - llp;
            }
        }
    }

    float tot = block_reduce(fac);
    if (tid == 0) atomicAdd(out, -tot);   // out zeroed by k0
}

extern "C" void kernel_launch(void* const* d_in, const int* in_sizes, int n_in,
                              void* d_out, int out_size, void* d_ws, size_t ws_size,
                              hipStream_t stream) {
    const float* scores = (const float*)d_in[0];   // [B, N, 2]
    const float* smap   = (const float*)d_in[1];   // [B, N]
    const float* gumbel = (const float*)d_in[2];   // [B, N, 2]
    float* out = (float*)d_out;

    // workspace: every region fully written before read except bdone/out,
    // which k0_init zeroes (workspace is poisoned, cannot assume zero)
    char* ws = (char*)d_ws;
    float*    pk1   = (float*)ws;    ws += (size_t)BATCH * SEGS * 4;            // 8KB
    float*    psel  = (float*)ws;    ws += (size_t)BATCH * SEGS * 4;            // 8KB
    float*    phi   = (float*)ws;    ws += (size_t)BATCH * SEGS * 4;            // 8KB
    uint32_t* gcc   = (uint32_t*)ws; ws += (size_t)BATCH * SEGS * 4;            // 8KB
    uint32_t* cvb   = (uint32_t*)ws; ws += (size_t)BATCH * NSLOT * 4;           // 1.5MB
    uint32_t* cvi   = (uint32_t*)ws; ws += (size_t)BATCH * NSLOT * 4;           // 1.5MB
    uint32_t* cvd   = (uint32_t*)ws; ws += (size_t)BATCH * NSLOT * 4;           // 1.5MB
    uint32_t* whist = (uint32_t*)ws; ws += (size_t)BATCH * SEGS * WHSTRIDE * 4; // 128KB
    uint32_t* bdone = (uint32_t*)ws; ws += (size_t)BATCH * 4;                   // 256B

    k0_init<<<1, 64, 0, stream>>>(bdone, out);

    k1_fused<<<BATCH * SEGS, 256, 0, stream>>>(
        (const float4*)scores, (const float4*)gumbel, (const float2*)smap,
        pk1, psel, phi, gcc, cvb, cvi, cvd, whist, bdone,
        (const float4*)smap, (const float2*)scores, (const float2*)gumbel, out);
}

// Round 2
// 120.888 us; speedup vs baseline: 2.7685x; 2.7685x over previous
//
#include <hip/hip_runtime.h>
#include <cstdint>

#define BATCH 64
#define NPIX 65536
#define TOPK 16384
#define NB 256
#define SEGS 32       // k1 blocks per batch
#define WLO 186       // candidate window low bin (threshold bin ~192)
#define WHI 198       // candidate window high bin
#define NWBIN (WHI - WLO + 1)
#define CAPB 192      // per-block window-candidate slots (expect ~104, sigma~10)
#define NSLOT (SEGS * CAPB)   // 6144
#define FCAP 1024     // threshold-bin rank buffer (expect ~256, sigma~16)
#define WHSTRIDE 16   // padded per-block histogram stride (13 used)

// ---- 256-thread block reduce (k1) ----
__device__ __forceinline__ float block_reduce(float acc) {
    __shared__ float w[4];
    __syncthreads();
    #pragma unroll
    for (int off = 32; off > 0; off >>= 1) acc += __shfl_down(acc, off, 64);
    if ((threadIdx.x & 63) == 0) w[threadIdx.x >> 6] = acc;
    __syncthreads();
    return w[0] + w[1] + w[2] + w[3];
}

// ---- 1024-thread block reduce (k4) ----
__device__ __forceinline__ float block_reduce1k(float acc) {
    __shared__ float w[16];
    __syncthreads();
    #pragma unroll
    for (int off = 32; off > 0; off >>= 1) acc += __shfl_down(acc, off, 64);
    if ((threadIdx.x & 63) == 0) w[threadIdx.x >> 6] = acc;
    __syncthreads();
    float s = 0.f;
    #pragma unroll
    for (int i = 0; i < 16; ++i) s += w[i];
    return s;
}

// p = softmax(a0,a1)[0] = sigmoid(d), d = a0-a1.
// lp = log p = min(d,0)-t ; llp = log(1-p) = -max(d,0)-t, t = log(1+exp(-|d|)).
__device__ __forceinline__ void bce_from_d(float d, float& lp, float& llp) {
    float t = __logf(1.f + __expf(-fabsf(d)));
    lp  = fmaxf(fminf(d, 0.f) - t, -100.f);
    llp = fmaxf(-fmaxf(d, 0.f) - t, -100.f);
}

__device__ __forceinline__ int vkey(float v) {
    return (int)fminf(v * 256.0f, 255.0f);   // monotone bucket map, v in [0,1)
}

// ---------------------------------------------------------------------------
// K1: EXACT round-9 kernel (proven fastest) + per-block 13-bin window
// histogram published to whist (lets k4 skip its pass A entirely).
// NO device fences — cross-kernel visibility comes from the dispatch
// boundary (round-1 post-mortem: per-block __threadfence = 2048 L2
// writeback/invalidate storms, 6x regression).
// Block 0 zeroes out[0].
// ---------------------------------------------------------------------------
__global__ __launch_bounds__(256) void k1_pass(
    const float4* __restrict__ sc, const float4* __restrict__ gn,
    const float2* __restrict__ tokp,
    float* __restrict__ pk1, float* __restrict__ psel, float* __restrict__ phi,
    uint32_t* __restrict__ gcc,
    uint32_t* __restrict__ cvb, uint32_t* __restrict__ cvi,
    uint32_t* __restrict__ cvd, uint32_t* __restrict__ whist,
    float* __restrict__ out)
{
    __shared__ uint32_t bvb[CAPB], bvi[CAPB], bvd[CAPB];
    __shared__ uint32_t sh_wh[NWBIN];
    __shared__ uint32_t ccount;
    const int tid = threadIdx.x;
    if (tid < CAPB) { bvb[tid] = 0u; bvi[tid] = 0u; bvd[tid] = 0u; }
    if (tid < NWBIN) sh_wh[tid] = 0u;
    if (tid == 0) { ccount = 0u; if (blockIdx.x == 0) out[0] = 0.f; }
    __syncthreads();

    const int b   = blockIdx.x >> 5;
    const int seg = blockIdx.x & (SEGS - 1);
    const int pairbase = b * (NPIX / 2) + seg * 1024;   // 1024 pairs / block
    float acc = 0.f, asel = 0.f, chi = 0.f;

    #pragma unroll
    for (int it = 0; it < 4; ++it) {
        int j = pairbase + it * 256 + tid;
        float4 s = sc[j];
        float4 g = gn[j];
        float2 tk = tokp[j];
        int px0 = (j - b * (NPIX / 2)) * 2;             // batch-local pixel idx
        {
            float d = (s.x + g.x) - (s.y + g.y);
            float lp, llp; bce_from_d(d, lp, llp);
            acc += llp;
            float diff = lp - llp;
            int k = vkey(tk.x);
            if (k > WHI) { asel += diff; chi += 1.f; }
            else if (k >= WLO) {
                uint32_t p = atomicAdd(&ccount, 1u);
                if (p < CAPB) {
                    bvb[p] = __float_as_uint(tk.x);
                    bvi[p] = (uint32_t)px0;
                    bvd[p] = __float_as_uint(diff);
                }
            }
        }
        {
            float d = (s.z + g.z) - (s.w + g.w);
            float lp, llp; bce_from_d(d, lp, llp);
            acc += llp;
            float diff = lp - llp;
            int k = vkey(tk.y);
            if (k > WHI) { asel += diff; chi += 1.f; }
            else if (k >= WLO) {
                uint32_t p = atomicAdd(&ccount, 1u);
                if (p < CAPB) {
                    bvb[p] = __float_as_uint(tk.y);
                    bvi[p] = (uint32_t)(px0 + 1);
                    bvd[p] = __float_as_uint(diff);
                }
            }
        }
    }
    __syncthreads();
    const uint32_t cc = ccount;
    // per-block window histogram from the compacted slots (~104 LDS atomics)
    {
        uint32_t nsl = cc < CAPB ? cc : CAPB;
        if (tid < nsl) {
            int k = vkey(__uint_as_float(bvb[tid]));
            atomicAdd(&sh_wh[k - WLO], 1u);
        }
    }
    // publish full fixed-size slot block (unused slots are zero sentinels)
    const size_t cbase = (size_t)blockIdx.x * CAPB;
    if (tid < CAPB) {
        cvb[cbase + tid] = bvb[tid];
        cvi[cbase + tid] = bvi[tid];
        cvd[cbase + tid] = bvd[tid];
    }
    if (tid == 0) gcc[blockIdx.x] = cc;

    float t1 = block_reduce(acc);    // internal barriers fence sh_wh atomics
    float t2 = block_reduce(asel);
    float t3 = block_reduce(chi);
    if (tid == 0) {
        pk1[blockIdx.x]  = t1;
        psel[blockIdx.x] = t2;
        phi[blockIdx.x]  = t3;
    }
    if (tid < NWBIN) whist[(size_t)blockIdx.x * WHSTRIDE + tid] = sh_wh[tid];
}

// ---------------------------------------------------------------------------
// K4: one 1024-THREAD block per batch (round-13 proven structure), minus
// pass A: window counts wc now come from summing the 32 per-block whist
// histograms (32x13 words) instead of re-reading all 6144 slots.
// Pass B: 6 loads/thread walk (L2/L3-hot): key>sb -> register diff sum;
// key==sb -> stage (~256 LDS atomics); cvd loaded unconditionally to break
// the conditional dependent-load chain. Exact rank under (value desc,
// index asc) == lax.top_k tie order. Exact full-rescan fallback
// (prob ~1e-10). One atomicAdd(-total) per batch into out (zeroed by k1).
// ---------------------------------------------------------------------------
__global__ __launch_bounds__(1024) void k4_finalize(
    const uint32_t* __restrict__ cvb, const uint32_t* __restrict__ cvi,
    const uint32_t* __restrict__ cvd, const uint32_t* __restrict__ gcc,
    const float* __restrict__ pk1, const float* __restrict__ psel,
    const float* __restrict__ phi, const uint32_t* __restrict__ whist,
    const float4* __restrict__ tok4,
    const float2* __restrict__ sc2, const float2* __restrict__ gn2,
    float* __restrict__ out)
{
    __shared__ uint32_t fvb[FCAP], fvi[FCAP];
    __shared__ float    fdf[FCAP];
    __shared__ uint32_t fh[NB];              // fallback histogram
    __shared__ uint32_t wc[NWBIN];
    __shared__ uint32_t fcnt;
    __shared__ int      sh_sb, sh_ovf;
    __shared__ uint32_t sh_rem;

    const int b = blockIdx.x, tid = threadIdx.x;
    if (tid == 0) { fcnt = 0u; sh_sb = -1; sh_ovf = 0; sh_rem = 1u; }
    __syncthreads();

    const size_t base = (size_t)b * NSLOT;

    // --- window counts from published per-block histograms (tiny) ---
    if (tid < SEGS && gcc[b * SEGS + tid] > CAPB) sh_ovf = 1;
    if (tid < NWBIN) {
        uint32_t u = 0;
        #pragma unroll
        for (int s = 0; s < SEGS; ++s)
            u += whist[(size_t)(b * SEGS + s) * WHSTRIDE + tid];
        wc[tid] = u;
    }
    float chl = (tid < SEGS) ? phi[b * SEGS + tid] : 0.f;
    float chf = block_reduce1k(chl);     // exact: integer-valued floats < 2^24
    if (tid == 0) {
        uint32_t cnt_hi = (uint32_t)(chf + 0.5f);
        if (cnt_hi >= TOPK) sh_ovf = 1;  // split bin above window
        else {
            uint32_t cum = cnt_hi;       // S[WHI+1]
            int found = -1; uint32_t rem = 1u;
            for (int jj = WHI; jj >= WLO; --jj) {
                uint32_t nc = cum + wc[jj - WLO];     // S[jj]
                if (nc >= TOPK) { found = jj; rem = TOPK - cum; break; }
                cum = nc;
            }
            if (found < 0) sh_ovf = 1;   // split bin below window
            else { sh_sb = found; sh_rem = rem; }
        }
    }
    __syncthreads();

    bool fast = (sh_ovf == 0);
    const int sb = sh_sb;
    float fac = (tid < SEGS) ? pk1[b * SEGS + tid] : 0.f;   // base llp

    if (fast) {
        if (tid < SEGS) fac += psel[b * SEGS + tid];        // key > WHI diffs
        // --- pass B: slot walk; >sb add diff; ==sb stage for rank ---
        #pragma unroll
        for (int it = 0; it < NSLOT / 1024; ++it) {
            int t = it * 1024 + tid;
            uint32_t vb = cvb[base + t];
            uint32_t vd = cvd[base + t];    // unconditional: no dep chain
            int k = vkey(__uint_as_float(vb));
            if (k > sb) fac += __uint_as_float(vd);
            else if (k == sb) {
                uint32_t p = atomicAdd(&fcnt, 1u);
                if (p < FCAP) {
                    fvb[p] = vb;
                    fvi[p] = cvi[base + t] & (NPIX - 1);
                    fdf[p] = __uint_as_float(vd);
                }
            }
        }
        __syncthreads();
        if (fcnt > FCAP) fast = false;   // uniform decision (shared value)
        if (fast) {
            const uint32_t cnt = fcnt, rem = sh_rem;
            for (uint32_t j = tid; j < cnt; j += 1024) {
                const uint32_t mb = fvb[j], mi = fvi[j];
                uint32_t rank = 0;
                for (uint32_t i = 0; i < cnt; ++i) {
                    uint32_t ob = fvb[i];
                    rank += (ob > mb) || (ob == mb && fvi[i] < mi);
                }
                if (rank < rem) fac += fdf[j];
            }
        }
    }

    if (!fast) {
        // ---- exact fallback: full per-batch recount + recompute ----
        fac = (tid < SEGS) ? pk1[b * SEGS + tid] : 0.f;     // reset to base
        for (int i = tid; i < NB; i += 1024) fh[i] = 0u;
        if (tid == 0) fcnt = 0u;
        __syncthreads();
        const float4* tbase = tok4 + (size_t)b * (NPIX / 4);
        for (int it = 0; it < NPIX / 4 / 1024; ++it) {
            float4 v = tbase[it * 1024 + tid];
            atomicAdd(&fh[vkey(v.x)], 1u);
            atomicAdd(&fh[vkey(v.y)], 1u);
            atomicAdd(&fh[vkey(v.z)], 1u);
            atomicAdd(&fh[vkey(v.w)], 1u);
        }
        __syncthreads();
        if (tid == 0) {
            uint32_t cum = 0; int bin = NB - 1;
            for (; bin > 0; --bin) {
                if (cum + fh[bin] >= TOPK) break;
                cum += fh[bin];
            }
            sh_sb = bin; sh_rem = TOPK - cum;
        }
        __syncthreads();
        const int sb2 = sh_sb; const uint32_t rem2 = sh_rem;
        for (int it = 0; it < NPIX / 4 / 1024; ++it) {
            int j = it * 1024 + tid;
            float4 v = tbase[j];
            int px = j * 4;
            float fv[4] = {v.x, v.y, v.z, v.w};
            #pragma unroll
            for (int q = 0; q < 4; ++q) {
                int k = vkey(fv[q]);
                if (k > sb2) {
                    size_t idx = (size_t)b * NPIX + (px + q);
                    float2 S = sc2[idx]; float2 G = gn2[idx];
                    float d = (S.x + G.x) - (S.y + G.y);
                    float lp, llp; bce_from_d(d, lp, llp);
                    fac += lp - llp;
                } else if (k == sb2) {
                    uint32_t p = atomicAdd(&fcnt, 1u);
                    if (p < FCAP) { fvb[p] = __float_as_uint(fv[q]); fvi[p] = (uint32_t)(px + q); }
                }
            }
        }
        __syncthreads();
        const uint32_t cnt2 = min(fcnt, (uint32_t)FCAP);
        for (uint32_t j = tid; j < cnt2; j += 1024) {
            const uint32_t mb = fvb[j], mi = fvi[j];
            uint32_t rank = 0;
            for (uint32_t i = 0; i < cnt2; ++i) {
                uint32_t ob = fvb[i];
                rank += (ob > mb) || (ob == mb && fvi[i] < mi);
            }
            if (rank < rem2) {
                size_t idx = (size_t)b * NPIX + (mi & (NPIX - 1));
                float2 S = sc2[idx]; float2 G = gn2[idx];
                float d = (S.x + G.x) - (S.y + G.y);
                float lp, llp; bce_from_d(d, lp, llp);
                fac += lp - llp;
            }
        }
    }

    float tot = block_reduce1k(fac);
    if (tid == 0) atomicAdd(out, -tot);   // 64 adds, out zeroed by k1
}

extern "C" void kernel_launch(void* const* d_in, const int* in_sizes, int n_in,
                              void* d_out, int out_size, void* d_ws, size_t ws_size,
                              hipStream_t stream) {
    const float* scores = (const float*)d_in[0];   // [B, N, 2]
    const float* smap   = (const float*)d_in[1];   // [B, N]
    const float* gumbel = (const float*)d_in[2];   // [B, N, 2]
    float* out = (float*)d_out;

    // workspace: every region fully written before read -> NO memset needed
    char* ws = (char*)d_ws;
    float*    pk1   = (float*)ws;    ws += (size_t)BATCH * SEGS * 4;            // 8KB
    float*    psel  = (float*)ws;    ws += (size_t)BATCH * SEGS * 4;            // 8KB
    float*    phi   = (float*)ws;    ws += (size_t)BATCH * SEGS * 4;            // 8KB
    uint32_t* gcc   = (uint32_t*)ws; ws += (size_t)BATCH * SEGS * 4;            // 8KB
    uint32_t* cvb   = (uint32_t*)ws; ws += (size_t)BATCH * NSLOT * 4;           // 1.5MB
    uint32_t* cvi   = (uint32_t*)ws; ws += (size_t)BATCH * NSLOT * 4;           // 1.5MB
    uint32_t* cvd   = (uint32_t*)ws; ws += (size_t)BATCH * NSLOT * 4;           // 1.5MB
    uint32_t* whist = (uint32_t*)ws; ws += (size_t)BATCH * SEGS * WHSTRIDE * 4; // 128KB

    k1_pass<<<BATCH * SEGS, 256, 0, stream>>>(
        (const float4*)scores, (const float4*)gumbel, (const float2*)smap,
        pk1, psel, phi, gcc, cvb, cvi, cvd, whist, out);

    k4_finalize<<<BATCH, 1024, 0, stream>>>(
        cvb, cvi, cvd, gcc, pk1, psel, phi, whist,
        (const float4*)smap, (const float2*)scores, (const float2*)gumbel, out);
}

// Round 3
// 118.746 us; speedup vs baseline: 2.8184x; 1.0180x over previous
//
#include <hip/hip_runtime.h>
#include <cstdint>

#define BATCH 64
#define NPIX 65536
#define TOPK 16384
#define NB 256
#define SEGS 32       // k1 blocks per batch
#define WLO 186       // candidate window low bin (threshold bin ~192)
#define WHI 198       // candidate window high bin
#define NWBIN (WHI - WLO + 1)
#define CAPB 192      // per-block window-candidate slots (expect ~104, sigma~10)
#define NSLOT (SEGS * CAPB)   // 6144
#define FCAP 1024     // threshold-bin rank buffer (expect ~256, sigma~16)
#define WHSTRIDE 16   // padded per-block histogram stride (13 used)

// ---- 256-thread block reduce (k1) ----
__device__ __forceinline__ float block_reduce(float acc) {
    __shared__ float w[4];
    __syncthreads();
    #pragma unroll
    for (int off = 32; off > 0; off >>= 1) acc += __shfl_down(acc, off, 64);
    if ((threadIdx.x & 63) == 0) w[threadIdx.x >> 6] = acc;
    __syncthreads();
    return w[0] + w[1] + w[2] + w[3];
}

// ---- 1024-thread block reduce (k4) ----
__device__ __forceinline__ float block_reduce1k(float acc) {
    __shared__ float w[16];
    __syncthreads();
    #pragma unroll
    for (int off = 32; off > 0; off >>= 1) acc += __shfl_down(acc, off, 64);
    if ((threadIdx.x & 63) == 0) w[threadIdx.x >> 6] = acc;
    __syncthreads();
    float s = 0.f;
    #pragma unroll
    for (int i = 0; i < 16; ++i) s += w[i];
    return s;
}

// p = softmax(a0,a1)[0] = sigmoid(d), d = a0-a1.
// lp = log p = min(d,0)-t ; llp = log(1-p) = -max(d,0)-t, t = log(1+exp(-|d|)).
__device__ __forceinline__ void bce_from_d(float d, float& lp, float& llp) {
    float t = __logf(1.f + __expf(-fabsf(d)));
    lp  = fmaxf(fminf(d, 0.f) - t, -100.f);
    llp = fmaxf(-fmaxf(d, 0.f) - t, -100.f);
}

__device__ __forceinline__ int vkey(float v) {
    return (int)fminf(v * 256.0f, 255.0f);   // monotone bucket map, v in [0,1)
}

// Wave-ballot compaction: one leader LDS atomic per 64-lane check instead of
// a serialized per-lane atomic chain. Slot ORDER differs from the serial
// version but slots are unordered by construction (k4 ranks by value/index);
// ccount total (overflow detection) is exact.
__device__ __forceinline__ void stage_candidate(
    bool inwin, float v, uint32_t pix, float diff, int lane,
    uint32_t* ccount, uint32_t* bvb, uint32_t* bvi, uint32_t* bvd)
{
    unsigned long long m = __ballot(inwin);
    if (m == 0ull) return;                       // wave-uniform skip
    uint32_t cnt = (uint32_t)__popcll(m);
    int leader = (int)__builtin_ctzll(m);
    uint32_t base = 0u;
    if (lane == leader) base = atomicAdd(ccount, cnt);
    base = (uint32_t)__shfl((int)base, leader, 64);
    if (inwin) {
        uint32_t p = base + (uint32_t)__popcll(m & ((1ull << lane) - 1ull));
        if (p < CAPB) {
            bvb[p] = __float_as_uint(v);
            bvi[p] = pix;
            bvd[p] = __float_as_uint(diff);
        }
    }
}

// ---------------------------------------------------------------------------
// K1: round-9 logic, restructured for memory-level parallelism.
// Round-2 post-mortem: VGPR_Count=32 proves the compiler interleaved
// load->compute per iteration (only ~40B/thread in flight; HBM latency
// exposed). Here: explicit depth-4 preload (12 loads issued back-to-back,
// 160B/thread in flight), then a pure-compute loop. __launch_bounds__(256,8)
// keeps VGPR<=64 so all 8 waves/SIMD stay resident.
// Block 0 zeroes out[0]. No device fences (round-1 lesson).
// ---------------------------------------------------------------------------
__global__ __launch_bounds__(256, 8) void k1_pass(
    const float4* __restrict__ sc, const float4* __restrict__ gn,
    const float2* __restrict__ tokp,
    float* __restrict__ pk1, float* __restrict__ psel, float* __restrict__ phi,
    uint32_t* __restrict__ gcc,
    uint32_t* __restrict__ cvb, uint32_t* __restrict__ cvi,
    uint32_t* __restrict__ cvd, uint32_t* __restrict__ whist,
    float* __restrict__ out)
{
    __shared__ uint32_t bvb[CAPB], bvi[CAPB], bvd[CAPB];
    __shared__ uint32_t sh_wh[NWBIN];
    __shared__ uint32_t ccount;
    const int tid  = threadIdx.x;
    const int lane = tid & 63;
    if (tid < CAPB) { bvb[tid] = 0u; bvi[tid] = 0u; bvd[tid] = 0u; }
    if (tid < NWBIN) sh_wh[tid] = 0u;
    if (tid == 0) { ccount = 0u; if (blockIdx.x == 0) out[0] = 0.f; }
    __syncthreads();

    const int b   = blockIdx.x >> 5;
    const int seg = blockIdx.x & (SEGS - 1);
    const int pairbase = b * (NPIX / 2) + seg * 1024;   // 1024 pairs / block

    // ---- phase 1: issue ALL loads (static indexing -> registers) ----
    float4 S[4], G[4];
    float2 T[4];
    #pragma unroll
    for (int it = 0; it < 4; ++it) {
        int j = pairbase + it * 256 + tid;
        S[it] = sc[j];
        G[it] = gn[j];
        T[it] = tokp[j];
    }

    // ---- phase 2: compute ----
    float acc = 0.f, asel = 0.f, chi = 0.f;
    #pragma unroll
    for (int it = 0; it < 4; ++it) {
        int px0 = (seg * 1024 + it * 256 + tid) * 2;    // batch-local pixel idx
        {
            float d = (S[it].x + G[it].x) - (S[it].y + G[it].y);
            float lp, llp; bce_from_d(d, lp, llp);
            acc += llp;
            float diff = lp - llp;
            int k = vkey(T[it].x);
            bool hi = (k > WHI);
            asel += hi ? diff : 0.f;
            chi  += hi ? 1.f : 0.f;
            stage_candidate(!hi && (k >= WLO), T[it].x, (uint32_t)px0, diff,
                            lane, &ccount, bvb, bvi, bvd);
        }
        {
            float d = (S[it].z + G[it].z) - (S[it].w + G[it].w);
            float lp, llp; bce_from_d(d, lp, llp);
            acc += llp;
            float diff = lp - llp;
            int k = vkey(T[it].y);
            bool hi = (k > WHI);
            asel += hi ? diff : 0.f;
            chi  += hi ? 1.f : 0.f;
            stage_candidate(!hi && (k >= WLO), T[it].y, (uint32_t)(px0 + 1), diff,
                            lane, &ccount, bvb, bvi, bvd);
        }
    }
    __syncthreads();
    const uint32_t cc = ccount;
    // per-block window histogram from the compacted slots (~104 LDS atomics)
    {
        uint32_t nsl = cc < CAPB ? cc : CAPB;
        if (tid < nsl) {
            int k = vkey(__uint_as_float(bvb[tid]));
            atomicAdd(&sh_wh[k - WLO], 1u);
        }
    }
    // publish full fixed-size slot block (unused slots are zero sentinels)
    const size_t cbase = (size_t)blockIdx.x * CAPB;
    if (tid < CAPB) {
        cvb[cbase + tid] = bvb[tid];
        cvi[cbase + tid] = bvi[tid];
        cvd[cbase + tid] = bvd[tid];
    }
    if (tid == 0) gcc[blockIdx.x] = cc;

    float t1 = block_reduce(acc);    // internal barriers fence sh_wh atomics
    float t2 = block_reduce(asel);
    float t3 = block_reduce(chi);
    if (tid == 0) {
        pk1[blockIdx.x]  = t1;
        psel[blockIdx.x] = t2;
        phi[blockIdx.x]  = t3;
    }
    if (tid < NWBIN) whist[(size_t)blockIdx.x * WHSTRIDE + tid] = sh_wh[tid];
}

// ---------------------------------------------------------------------------
// K4: one 1024-THREAD block per batch (proven round-2 version, unchanged).
// wc from summed per-block whist histograms; pass B slot walk with
// unconditional cvd load; exact rank; exact full-rescan fallback.
// ---------------------------------------------------------------------------
__global__ __launch_bounds__(1024) void k4_finalize(
    const uint32_t* __restrict__ cvb, const uint32_t* __restrict__ cvi,
    const uint32_t* __restrict__ cvd, const uint32_t* __restrict__ gcc,
    const float* __restrict__ pk1, const float* __restrict__ psel,
    const float* __restrict__ phi, const uint32_t* __restrict__ whist,
    const float4* __restrict__ tok4,
    const float2* __restrict__ sc2, const float2* __restrict__ gn2,
    float* __restrict__ out)
{
    __shared__ uint32_t fvb[FCAP], fvi[FCAP];
    __shared__ float    fdf[FCAP];
    __shared__ uint32_t fh[NB];              // fallback histogram
    __shared__ uint32_t wc[NWBIN];
    __shared__ uint32_t fcnt;
    __shared__ int      sh_sb, sh_ovf;
    __shared__ uint32_t sh_rem;

    const int b = blockIdx.x, tid = threadIdx.x;
    if (tid == 0) { fcnt = 0u; sh_sb = -1; sh_ovf = 0; sh_rem = 1u; }
    __syncthreads();

    const size_t base = (size_t)b * NSLOT;

    // --- window counts from published per-block histograms (tiny) ---
    if (tid < SEGS && gcc[b * SEGS + tid] > CAPB) sh_ovf = 1;
    if (tid < NWBIN) {
        uint32_t u = 0;
        #pragma unroll
        for (int s = 0; s < SEGS; ++s)
            u += whist[(size_t)(b * SEGS + s) * WHSTRIDE + tid];
        wc[tid] = u;
    }
    float chl = (tid < SEGS) ? phi[b * SEGS + tid] : 0.f;
    float chf = block_reduce1k(chl);     // exact: integer-valued floats < 2^24
    if (tid == 0) {
        uint32_t cnt_hi = (uint32_t)(chf + 0.5f);
        if (cnt_hi >= TOPK) sh_ovf = 1;  // split bin above window
        else {
            uint32_t cum = cnt_hi;       // S[WHI+1]
            int found = -1; uint32_t rem = 1u;
            for (int jj = WHI; jj >= WLO; --jj) {
                uint32_t nc = cum + wc[jj - WLO];     // S[jj]
                if (nc >= TOPK) { found = jj; rem = TOPK - cum; break; }
                cum = nc;
            }
            if (found < 0) sh_ovf = 1;   // split bin below window
            else { sh_sb = found; sh_rem = rem; }
        }
    }
    __syncthreads();

    bool fast = (sh_ovf == 0);
    const int sb = sh_sb;
    float fac = (tid < SEGS) ? pk1[b * SEGS + tid] : 0.f;   // base llp

    if (fast) {
        if (tid < SEGS) fac += psel[b * SEGS + tid];        // key > WHI diffs
        // --- pass B: slot walk; >sb add diff; ==sb stage for rank ---
        #pragma unroll
        for (int it = 0; it < NSLOT / 1024; ++it) {
            int t = it * 1024 + tid;
            uint32_t vb = cvb[base + t];
            uint32_t vd = cvd[base + t];    // unconditional: no dep chain
            int k = vkey(__uint_as_float(vb));
            if (k > sb) fac += __uint_as_float(vd);
            else if (k == sb) {
                uint32_t p = atomicAdd(&fcnt, 1u);
                if (p < FCAP) {
                    fvb[p] = vb;
                    fvi[p] = cvi[base + t] & (NPIX - 1);
                    fdf[p] = __uint_as_float(vd);
                }
            }
        }
        __syncthreads();
        if (fcnt > FCAP) fast = false;   // uniform decision (shared value)
        if (fast) {
            const uint32_t cnt = fcnt, rem = sh_rem;
            for (uint32_t j = tid; j < cnt; j += 1024) {
                const uint32_t mb = fvb[j], mi = fvi[j];
                uint32_t rank = 0;
                for (uint32_t i = 0; i < cnt; ++i) {
                    uint32_t ob = fvb[i];
                    rank += (ob > mb) || (ob == mb && fvi[i] < mi);
                }
                if (rank < rem) fac += fdf[j];
            }
        }
    }

    if (!fast) {
        // ---- exact fallback: full per-batch recount + recompute ----
        fac = (tid < SEGS) ? pk1[b * SEGS + tid] : 0.f;     // reset to base
        for (int i = tid; i < NB; i += 1024) fh[i] = 0u;
        if (tid == 0) fcnt = 0u;
        __syncthreads();
        const float4* tbase = tok4 + (size_t)b * (NPIX / 4);
        for (int it = 0; it < NPIX / 4 / 1024; ++it) {
            float4 v = tbase[it * 1024 + tid];
            atomicAdd(&fh[vkey(v.x)], 1u);
            atomicAdd(&fh[vkey(v.y)], 1u);
            atomicAdd(&fh[vkey(v.z)], 1u);
            atomicAdd(&fh[vkey(v.w)], 1u);
        }
        __syncthreads();
        if (tid == 0) {
            uint32_t cum = 0; int bin = NB - 1;
            for (; bin > 0; --bin) {
                if (cum + fh[bin] >= TOPK) break;
                cum += fh[bin];
            }
            sh_sb = bin; sh_rem = TOPK - cum;
        }
        __syncthreads();
        const int sb2 = sh_sb; const uint32_t rem2 = sh_rem;
        for (int it = 0; it < NPIX / 4 / 1024; ++it) {
            int j = it * 1024 + tid;
            float4 v = tbase[j];
            int px = j * 4;
            float fv[4] = {v.x, v.y, v.z, v.w};
            #pragma unroll
            for (int q = 0; q < 4; ++q) {
                int k = vkey(fv[q]);
                if (k > sb2) {
                    size_t idx = (size_t)b * NPIX + (px + q);
                    float2 Sv = sc2[idx]; float2 Gv = gn2[idx];
                    float d = (Sv.x + Gv.x) - (Sv.y + Gv.y);
                    float lp, llp; bce_from_d(d, lp, llp);
                    fac += lp - llp;
                } else if (k == sb2) {
                    uint32_t p = atomicAdd(&fcnt, 1u);
                    if (p < FCAP) { fvb[p] = __float_as_uint(fv[q]); fvi[p] = (uint32_t)(px + q); }
                }
            }
        }
        __syncthreads();
        const uint32_t cnt2 = min(fcnt, (uint32_t)FCAP);
        for (uint32_t j = tid; j < cnt2; j += 1024) {
            const uint32_t mb = fvb[j], mi = fvi[j];
            uint32_t rank = 0;
            for (uint32_t i = 0; i < cnt2; ++i) {
                uint32_t ob = fvb[i];
                rank += (ob > mb) || (ob == mb && fvi[i] < mi);
            }
            if (rank < rem2) {
                size_t idx = (size_t)b * NPIX + (mi & (NPIX - 1));
                float2 Sv = sc2[idx]; float2 Gv = gn2[idx];
                float d = (Sv.x + Gv.x) - (Sv.y + Gv.y);
                float lp, llp; bce_from_d(d, lp, llp);
                fac += lp - llp;
            }
        }
    }

    float tot = block_reduce1k(fac);
    if (tid == 0) atomicAdd(out, -tot);   // 64 adds, out zeroed by k1
}

extern "C" void kernel_launch(void* const* d_in, const int* in_sizes, int n_in,
                              void* d_out, int out_size, void* d_ws, size_t ws_size,
                              hipStream_t stream) {
    const float* scores = (const float*)d_in[0];   // [B, N, 2]
    const float* smap   = (const float*)d_in[1];   // [B, N]
    const float* gumbel = (const float*)d_in[2];   // [B, N, 2]
    float* out = (float*)d_out;

    // workspace: every region fully written before read -> NO memset needed
    char* ws = (char*)d_ws;
    float*    pk1   = (float*)ws;    ws += (size_t)BATCH * SEGS * 4;            // 8KB
    float*    psel  = (float*)ws;    ws += (size_t)BATCH * SEGS * 4;            // 8KB
    float*    phi   = (float*)ws;    ws += (size_t)BATCH * SEGS * 4;            // 8KB
    uint32_t* gcc   = (uint32_t*)ws; ws += (size_t)BATCH * SEGS * 4;            // 8KB
    uint32_t* cvb   = (uint32_t*)ws; ws += (size_t)BATCH * NSLOT * 4;           // 1.5MB
    uint32_t* cvi   = (uint32_t*)ws; ws += (size_t)BATCH * NSLOT * 4;           // 1.5MB
    uint32_t* cvd   = (uint32_t*)ws; ws += (size_t)BATCH * NSLOT * 4;           // 1.5MB
    uint32_t* whist = (uint32_t*)ws; ws += (size_t)BATCH * SEGS * WHSTRIDE * 4; // 128KB

    k1_pass<<<BATCH * SEGS, 256, 0, stream>>>(
        (const float4*)scores, (const float4*)gumbel, (const float2*)smap,
        pk1, psel, phi, gcc, cvb, cvi, cvd, whist, out);

    k4_finalize<<<BATCH, 1024, 0, stream>>>(
        cvb, cvi, cvd, gcc, pk1, psel, phi, whist,
        (const float4*)smap, (const float2*)scores, (const float2*)gumbel, out);
}

// Round 4
// 117.347 us; speedup vs baseline: 2.8521x; 1.0119x over previous
//
#include <hip/hip_runtime.h>
#include <cstdint>

#define BATCH 64
#define NPIX 65536
#define TOPK 16384
#define NB 256
#define SEGS 32       // k1 blocks per batch
#define WLO 186       // candidate window low bin (threshold bin ~192)
#define WHI 198       // candidate window high bin
#define NWBIN (WHI - WLO + 1)
#define CAPB 192      // per-block window-candidate slots (expect ~104, sigma~10)
#define NSLOT (SEGS * CAPB)   // 6144
#define FCAP 1024     // threshold-bin rank buffer (expect ~256, sigma~16)
#define WHSTRIDE 16   // padded per-block histogram stride (13 used)

// ---- 256-thread block reduce (k1) ----
__device__ __forceinline__ float block_reduce(float acc) {
    __shared__ float w[4];
    __syncthreads();
    #pragma unroll
    for (int off = 32; off > 0; off >>= 1) acc += __shfl_down(acc, off, 64);
    if ((threadIdx.x & 63) == 0) w[threadIdx.x >> 6] = acc;
    __syncthreads();
    return w[0] + w[1] + w[2] + w[3];
}

// ---- 1024-thread block reduce (k4) ----
__device__ __forceinline__ float block_reduce1k(float acc) {
    __shared__ float w[16];
    __syncthreads();
    #pragma unroll
    for (int off = 32; off > 0; off >>= 1) acc += __shfl_down(acc, off, 64);
    if ((threadIdx.x & 63) == 0) w[threadIdx.x >> 6] = acc;
    __syncthreads();
    float s = 0.f;
    #pragma unroll
    for (int i = 0; i < 16; ++i) s += w[i];
    return s;
}

// p = softmax(a0,a1)[0] = sigmoid(d), d = a0-a1.
// lp = log p = min(d,0)-t ; llp = log(1-p) = -max(d,0)-t, t = log(1+exp(-|d|)).
__device__ __forceinline__ void bce_from_d(float d, float& lp, float& llp) {
    float t = __logf(1.f + __expf(-fabsf(d)));
    lp  = fmaxf(fminf(d, 0.f) - t, -100.f);
    llp = fmaxf(-fmaxf(d, 0.f) - t, -100.f);
}

__device__ __forceinline__ int vkey(float v) {
    return (int)fminf(v * 256.0f, 255.0f);   // monotone bucket map, v in [0,1)
}

// Wave-ballot compaction: one leader LDS atomic per 64-lane check instead of
// a serialized per-lane atomic chain. Slot order is arbitrary (k4 ranks by
// value/index); ccount total (overflow detection) is exact.
__device__ __forceinline__ void stage_candidate(
    bool inwin, float v, uint32_t pix, float diff, int lane,
    uint32_t* ccount, uint32_t* bvb, uint32_t* bvi, uint32_t* bvd)
{
    unsigned long long m = __ballot(inwin);
    if (m == 0ull) return;                       // wave-uniform skip
    uint32_t cnt = (uint32_t)__popcll(m);
    int leader = (int)__builtin_ctzll(m);
    uint32_t base = 0u;
    if (lane == leader) base = atomicAdd(ccount, cnt);
    base = (uint32_t)__shfl((int)base, leader, 64);
    if (inwin) {
        uint32_t p = base + (uint32_t)__popcll(m & ((1ull << lane) - 1ull));
        if (p < CAPB) {
            bvb[p] = __float_as_uint(v);
            bvi[p] = pix;
            bvd[p] = __float_as_uint(diff);
        }
    }
}

// ---------------------------------------------------------------------------
// K1: round-3 main pass (ballot staging, depth-4 preload) + BUCKETED publish:
// slots are scattered into bin-sorted order before publishing, and per-bin
// diff-sums (wdsum) are published alongside the per-bin counts (whist).
// This lets k4 skip the full slot walk: bins>sb are precomputed sums, only
// the ==sb bucket (~8 entries/block) is ever gathered.
// Block 0 zeroes out[0]. No device fences (round-1 lesson).
// ---------------------------------------------------------------------------
__global__ __launch_bounds__(256, 8) void k1_pass(
    const float4* __restrict__ sc, const float4* __restrict__ gn,
    const float2* __restrict__ tokp,
    float* __restrict__ pk1, float* __restrict__ psel, float* __restrict__ phi,
    uint32_t* __restrict__ gcc,
    uint32_t* __restrict__ cvb, uint32_t* __restrict__ cvi,
    uint32_t* __restrict__ cvd, uint32_t* __restrict__ whist,
    float* __restrict__ wdsumg,
    float* __restrict__ out)
{
    __shared__ uint32_t bvb[CAPB], bvi[CAPB], bvd[CAPB];    // staging order
    __shared__ uint32_t qvb[CAPB], qvi[CAPB], qvd[CAPB];    // bucketed order
    __shared__ uint32_t sh_wh[NWBIN], sh_pref[NWBIN], sh_cur[NWBIN];
    __shared__ float    sh_wds[NWBIN];
    __shared__ uint32_t ccount;
    const int tid  = threadIdx.x;
    const int lane = tid & 63;
    if (tid < CAPB) { qvb[tid] = 0u; qvi[tid] = 0u; qvd[tid] = 0u; }
    if (tid < NWBIN) { sh_wh[tid] = 0u; sh_cur[tid] = 0u; sh_wds[tid] = 0.f; }
    if (tid == 0) { ccount = 0u; if (blockIdx.x == 0) out[0] = 0.f; }
    __syncthreads();

    const int b   = blockIdx.x >> 5;
    const int seg = blockIdx.x & (SEGS - 1);
    const int pairbase = b * (NPIX / 2) + seg * 1024;   // 1024 pairs / block

    // ---- phase 1: issue ALL loads (static indexing -> registers) ----
    float4 S[4], G[4];
    float2 T[4];
    #pragma unroll
    for (int it = 0; it < 4; ++it) {
        int j = pairbase + it * 256 + tid;
        S[it] = sc[j];
        G[it] = gn[j];
        T[it] = tokp[j];
    }

    // ---- phase 2: compute ----
    float acc = 0.f, asel = 0.f, chi = 0.f;
    #pragma unroll
    for (int it = 0; it < 4; ++it) {
        int px0 = (seg * 1024 + it * 256 + tid) * 2;    // batch-local pixel idx
        {
            float d = (S[it].x + G[it].x) - (S[it].y + G[it].y);
            float lp, llp; bce_from_d(d, lp, llp);
            acc += llp;
            float diff = lp - llp;
            int k = vkey(T[it].x);
            bool hi = (k > WHI);
            asel += hi ? diff : 0.f;
            chi  += hi ? 1.f : 0.f;
            stage_candidate(!hi && (k >= WLO), T[it].x, (uint32_t)px0, diff,
                            lane, &ccount, bvb, bvi, bvd);
        }
        {
            float d = (S[it].z + G[it].z) - (S[it].w + G[it].w);
            float lp, llp; bce_from_d(d, lp, llp);
            acc += llp;
            float diff = lp - llp;
            int k = vkey(T[it].y);
            bool hi = (k > WHI);
            asel += hi ? diff : 0.f;
            chi  += hi ? 1.f : 0.f;
            stage_candidate(!hi && (k >= WLO), T[it].y, (uint32_t)(px0 + 1), diff,
                            lane, &ccount, bvb, bvi, bvd);
        }
    }
    __syncthreads();
    const uint32_t cc  = ccount;
    const uint32_t nsl = cc < CAPB ? cc : CAPB;
    // bin histogram over stored slots (~104 LDS atomics)
    if (tid < nsl) {
        int k = vkey(__uint_as_float(bvb[tid]));
        atomicAdd(&sh_wh[k - WLO], 1u);
    }
    __syncthreads();
    // exclusive prefix over 13 bins (serial, trivial)
    if (tid == 0) {
        uint32_t run = 0;
        #pragma unroll
        for (int i = 0; i < NWBIN; ++i) { sh_pref[i] = run; run += sh_wh[i]; }
    }
    __syncthreads();
    // scatter slots into bucketed order + per-bin diff sums
    if (tid < nsl) {
        uint32_t vb = bvb[tid];
        int bin = vkey(__uint_as_float(vb)) - WLO;
        uint32_t pos = sh_pref[bin] + atomicAdd(&sh_cur[bin], 1u);
        qvb[pos] = vb;
        qvi[pos] = bvi[tid];
        qvd[pos] = bvd[tid];
        atomicAdd(&sh_wds[bin], __uint_as_float(bvd[tid]));
    }
    __syncthreads();
    // publish bucketed fixed-size block (unused slots are zero sentinels)
    const size_t cbase = (size_t)blockIdx.x * CAPB;
    if (tid < CAPB) {
        cvb[cbase + tid] = qvb[tid];
        cvi[cbase + tid] = qvi[tid];
        cvd[cbase + tid] = qvd[tid];
    }
    if (tid == 0) gcc[blockIdx.x] = cc;

    float t1 = block_reduce(acc);
    float t2 = block_reduce(asel);
    float t3 = block_reduce(chi);
    if (tid == 0) {
        pk1[blockIdx.x]  = t1;
        psel[blockIdx.x] = t2;
        phi[blockIdx.x]  = t3;
    }
    if (tid < NWBIN) {
        whist[(size_t)blockIdx.x * WHSTRIDE + tid]  = sh_wh[tid];
        wdsumg[(size_t)blockIdx.x * WHSTRIDE + tid] = sh_wds[tid];
    }
}

// ---------------------------------------------------------------------------
// K4 (skinny): no slot walk. wc from whist; bins>sb from precomputed wdsum
// (<=384 float reads); ==sb bucket gathered via per-seg prefix offsets
// (~256 entries). Exact rank under (value desc, index asc) == lax.top_k tie
// order. Exact full-rescan fallback on any overflow (prob ~1e-10).
// ---------------------------------------------------------------------------
__global__ __launch_bounds__(1024) void k4_finalize(
    const uint32_t* __restrict__ cvb, const uint32_t* __restrict__ cvi,
    const uint32_t* __restrict__ cvd, const uint32_t* __restrict__ gcc,
    const float* __restrict__ pk1, const float* __restrict__ psel,
    const float* __restrict__ phi, const uint32_t* __restrict__ whist,
    const float* __restrict__ wdsumg,
    const float4* __restrict__ tok4,
    const float2* __restrict__ sc2, const float2* __restrict__ gn2,
    float* __restrict__ out)
{
    __shared__ uint32_t fvb[FCAP], fvi[FCAP];
    __shared__ float    fdf[FCAP];
    __shared__ uint32_t fh[NB];              // fallback histogram
    __shared__ uint32_t wc[NWBIN];
    __shared__ uint32_t segstart[SEGS], segcnt[SEGS];
    __shared__ uint32_t fcnt;
    __shared__ int      sh_sb, sh_ovf;
    __shared__ uint32_t sh_rem;

    const int b = blockIdx.x, tid = threadIdx.x;
    if (tid == 0) { fcnt = 0u; sh_sb = -1; sh_ovf = 0; sh_rem = 1u; }
    __syncthreads();

    // --- window counts from published per-block histograms (tiny) ---
    if (tid < SEGS && gcc[b * SEGS + tid] > CAPB) sh_ovf = 1;
    if (tid < NWBIN) {
        uint32_t u = 0;
        #pragma unroll
        for (int s = 0; s < SEGS; ++s)
            u += whist[(size_t)(b * SEGS + s) * WHSTRIDE + tid];
        wc[tid] = u;
    }
    float chl = (tid < SEGS) ? phi[b * SEGS + tid] : 0.f;
    float chf = block_reduce1k(chl);     // exact: integer-valued floats < 2^24
    if (tid == 0) {
        uint32_t cnt_hi = (uint32_t)(chf + 0.5f);
        if (cnt_hi >= TOPK) sh_ovf = 1;  // split bin above window
        else {
            uint32_t cum = cnt_hi;       // S[WHI+1]
            int found = -1; uint32_t rem = 1u;
            for (int jj = WHI; jj >= WLO; --jj) {
                uint32_t nc = cum + wc[jj - WLO];     // S[jj]
                if (nc >= TOPK) { found = jj; rem = TOPK - cum; break; }
                cum = nc;
            }
            if (found < 0) sh_ovf = 1;   // split bin below window
            else { sh_sb = found; sh_rem = rem; }
        }
    }
    __syncthreads();

    bool fast = (sh_ovf == 0);
    const int sb  = sh_sb;
    const int sbi = sb - WLO;
    float fac = (tid < SEGS) ? pk1[b * SEGS + tid] : 0.f;   // base llp

    if (fast) {
        if (tid < SEGS) fac += psel[b * SEGS + tid];        // key > WHI diffs
        // bins > sb: precomputed per-block diff sums (<=384 reads)
        if (tid < SEGS * WHSTRIDE) {
            int s = tid >> 4, bin = tid & 15;
            if (bin < NWBIN && bin > sbi)
                fac += wdsumg[(size_t)(b * SEGS + s) * WHSTRIDE + bin];
        }
        // per-seg offset of the ==sb bucket (prefix of seg's whist row)
        if (tid < SEGS) {
            uint32_t st = 0;
            for (int i = 0; i < sbi; ++i)
                st += whist[(size_t)(b * SEGS + tid) * WHSTRIDE + i];
            segstart[tid] = st;
            segcnt[tid]   = whist[(size_t)(b * SEGS + tid) * WHSTRIDE + sbi];
        }
        __syncthreads();
        // gather ==sb bucket entries (~256 total); 32-thread group per seg
        {
            int g = tid >> 5, l32 = tid & 31;
            uint32_t c = segcnt[g];
            size_t sbase = (size_t)(b * SEGS + g) * CAPB + segstart[g];
            for (uint32_t i = l32; i < c; i += 32) {
                uint32_t p = atomicAdd(&fcnt, 1u);
                if (p < FCAP) {
                    fvb[p] = cvb[sbase + i];
                    fvi[p] = cvi[sbase + i] & (NPIX - 1);
                    fdf[p] = __uint_as_float(cvd[sbase + i]);
                }
            }
        }
        __syncthreads();
        if (fcnt > FCAP) fast = false;   // uniform decision (shared value)
        if (fast) {
            const uint32_t cnt = fcnt, rem = sh_rem;
            for (uint32_t j = tid; j < cnt; j += 1024) {
                const uint32_t mb = fvb[j], mi = fvi[j];
                uint32_t rank = 0;
                for (uint32_t i = 0; i < cnt; ++i) {
                    uint32_t ob = fvb[i];
                    rank += (ob > mb) || (ob == mb && fvi[i] < mi);
                }
                if (rank < rem) fac += fdf[j];
            }
        }
    }

    if (!fast) {
        // ---- exact fallback: full per-batch recount + recompute ----
        fac = (tid < SEGS) ? pk1[b * SEGS + tid] : 0.f;     // reset to base
        for (int i = tid; i < NB; i += 1024) fh[i] = 0u;
        if (tid == 0) fcnt = 0u;
        __syncthreads();
        const float4* tbase = tok4 + (size_t)b * (NPIX / 4);
        for (int it = 0; it < NPIX / 4 / 1024; ++it) {
            float4 v = tbase[it * 1024 + tid];
            atomicAdd(&fh[vkey(v.x)], 1u);
            atomicAdd(&fh[vkey(v.y)], 1u);
            atomicAdd(&fh[vkey(v.z)], 1u);
            atomicAdd(&fh[vkey(v.w)], 1u);
        }
        __syncthreads();
        if (tid == 0) {
            uint32_t cum = 0; int bin = NB - 1;
            for (; bin > 0; --bin) {
                if (cum + fh[bin] >= TOPK) break;
                cum += fh[bin];
            }
            sh_sb = bin; sh_rem = TOPK - cum;
        }
        __syncthreads();
        const int sb2 = sh_sb; const uint32_t rem2 = sh_rem;
        for (int it = 0; it < NPIX / 4 / 1024; ++it) {
            int j = it * 1024 + tid;
            float4 v = tbase[j];
            int px = j * 4;
            float fv[4] = {v.x, v.y, v.z, v.w};
            #pragma unroll
            for (int q = 0; q < 4; ++q) {
                int k = vkey(fv[q]);
                if (k > sb2) {
                    size_t idx = (size_t)b * NPIX + (px + q);
                    float2 Sv = sc2[idx]; float2 Gv = gn2[idx];
                    float d = (Sv.x + Gv.x) - (Sv.y + Gv.y);
                    float lp, llp; bce_from_d(d, lp, llp);
                    fac += lp - llp;
                } else if (k == sb2) {
                    uint32_t p = atomicAdd(&fcnt, 1u);
                    if (p < FCAP) { fvb[p] = __float_as_uint(fv[q]); fvi[p] = (uint32_t)(px + q); }
                }
            }
        }
        __syncthreads();
        const uint32_t cnt2 = min(fcnt, (uint32_t)FCAP);
        for (uint32_t j = tid; j < cnt2; j += 1024) {
            const uint32_t mb = fvb[j], mi = fvi[j];
            uint32_t rank = 0;
            for (uint32_t i = 0; i < cnt2; ++i) {
                uint32_t ob = fvb[i];
                rank += (ob > mb) || (ob == mb && fvi[i] < mi);
            }
            if (rank < rem2) {
                size_t idx = (size_t)b * NPIX + (mi & (NPIX - 1));
                float2 Sv = sc2[idx]; float2 Gv = gn2[idx];
                float d = (Sv.x + Gv.x) - (Sv.y + Gv.y);
                float lp, llp; bce_from_d(d, lp, llp);
                fac += lp - llp;
            }
        }
    }

    float tot = block_reduce1k(fac);
    if (tid == 0) atomicAdd(out, -tot);   // 64 adds, out zeroed by k1
}

extern "C" void kernel_launch(void* const* d_in, const int* in_sizes, int n_in,
                              void* d_out, int out_size, void* d_ws, size_t ws_size,
                              hipStream_t stream) {
    const float* scores = (const float*)d_in[0];   // [B, N, 2]
    const float* smap   = (const float*)d_in[1];   // [B, N]
    const float* gumbel = (const float*)d_in[2];   // [B, N, 2]
    float* out = (float*)d_out;

    // workspace: every region fully written before read -> NO memset needed
    char* ws = (char*)d_ws;
    float*    pk1   = (float*)ws;    ws += (size_t)BATCH * SEGS * 4;            // 8KB
    float*    psel  = (float*)ws;    ws += (size_t)BATCH * SEGS * 4;            // 8KB
    float*    phi   = (float*)ws;    ws += (size_t)BATCH * SEGS * 4;            // 8KB
    uint32_t* gcc   = (uint32_t*)ws; ws += (size_t)BATCH * SEGS * 4;            // 8KB
    uint32_t* cvb   = (uint32_t*)ws; ws += (size_t)BATCH * NSLOT * 4;           // 1.5MB
    uint32_t* cvi   = (uint32_t*)ws; ws += (size_t)BATCH * NSLOT * 4;           // 1.5MB
    uint32_t* cvd   = (uint32_t*)ws; ws += (size_t)BATCH * NSLOT * 4;           // 1.5MB
    uint32_t* whist = (uint32_t*)ws; ws += (size_t)BATCH * SEGS * WHSTRIDE * 4; // 128KB
    float*    wdsum = (float*)ws;    ws += (size_t)BATCH * SEGS * WHSTRIDE * 4; // 128KB

    k1_pass<<<BATCH * SEGS, 256, 0, stream>>>(
        (const float4*)scores, (const float4*)gumbel, (const float2*)smap,
        pk1, psel, phi, gcc, cvb, cvi, cvd, whist, wdsum, out);

    k4_finalize<<<BATCH, 1024, 0, stream>>>(
        cvb, cvi, cvd, gcc, pk1, psel, phi, whist, wdsum,
        (const float4*)smap, (const float2*)scores, (const float2*)gumbel, out);
}